// Round 5
// baseline (193.432 us; speedup 1.0000x reference)
//
#include <hip/hip_runtime.h>
#include <hip/hip_bf16.h>

// Sparse Conv3d(32,32,k=2,s=2) kernel-map form:
//   out[out_idx[p], d] += sum_c x[p,c] * W[k_idx[p], c, d]
//
// R5: atomic-free inverse-map design. k=2,s=2 -> each point owns a unique
// (out_voxel, k) slot; child[o][k]=p built with plain stores. New vs R4:
// x is pre-converted to bf16 (51 MB) in a STREAMING pass fused into the
// map-build kernel. The gather kernel then pulls one 16B bf16 fragment per
// lane per k (half the random bytes of R4, L3-warm because we just wrote it,
// no pack VALU, 32 data VGPRs -> loads provably batch). 16x16x32 bf16 MFMA
// per k, plain stores, no atomics, no d_out memset.

typedef __attribute__((ext_vector_type(8))) short bf16x8;   // 8 bf16 = 4 VGPRs
typedef __attribute__((ext_vector_type(4))) float f32x4;    // 4 fp32 acc

union ABFrag { bf16x8 v; int i[4]; };
union BFI { __hip_bfloat162 h; int i; };

__device__ __forceinline__ int pack2_bf16(float a, float b) {
    BFI u; u.h = __float22bfloat162_rn(make_float2(a, b));   // h.x=lo, h.y=hi
    return u.i;
}

__device__ __forceinline__ unsigned short f2bf(float f) {
    union { float f; unsigned u; } v; v.f = f;
    unsigned r = v.u + 0x7FFFu + ((v.u >> 16) & 1u);   // RNE
    return (unsigned short)(r >> 16);
}

// Fused: (a) repack W[k][c][d] fp32 -> WB in B-fragment lane order (16 KB):
// WB[((k*2+half)*64 + lane)*8 + j] = bf16(W[k][(lane>>4)*8+j][half*16+(lane&15)])
// (b) grid-stride fill of child map with -1 (int4 stores).
__global__ __launch_bounds__(256) void prep_fill_kernel(
    const float* __restrict__ W, unsigned short* __restrict__ WB,
    int4* __restrict__ child4, int n4) {
    int t = blockIdx.x * blockDim.x + threadIdx.x;
    if (t < 8 * 2 * 64 * 8) {
        int j    = t & 7;
        int lane = (t >> 3) & 63;
        int half = (t >> 9) & 1;
        int k    = t >> 10;
        int c = (lane >> 4) * 8 + j;
        int d = half * 16 + (lane & 15);
        WB[t] = f2bf(W[k * 1024 + c * 32 + d]);
    }
    const int4 m1 = make_int4(-1, -1, -1, -1);
    for (int i = t; i < n4; i += gridDim.x * blockDim.x) child4[i] = m1;
}

// Fused streaming pass: (a) inverse map (plain store, unique slots);
// (b) x fp32 -> bf16 copy (float4 in, int2 out), fully coalesced.
__global__ __launch_bounds__(256) void convert_build_kernel(
    const float4* __restrict__ x4, int2* __restrict__ xb2,
    const int* __restrict__ k_idx, const int* __restrict__ out_idx,
    int* __restrict__ child, int n) {
    int t = blockIdx.x * blockDim.x + threadIdx.x;
    if (t < n) child[(size_t)out_idx[t] * 8 + k_idx[t]] = t;
    const int n4 = n * 8;                       // float4 chunks (n*32/4)
    const int stride = gridDim.x * blockDim.x;
    for (int i = t; i < n4; i += stride) {
        float4 v = x4[i];
        xb2[i] = make_int2(pack2_bf16(v.x, v.y), pack2_bf16(v.z, v.w));
    }
}

__global__ __launch_bounds__(256, 4) void conv_gather_kernel(
    const unsigned short* __restrict__ xb,    // bf16 x, row-major n x 32
    const unsigned short* __restrict__ WB,
    const int* __restrict__ child,
    float* __restrict__ out,
    int num_out)
{
    const int lane  = threadIdx.x & 63;
    const int wv    = threadIdx.x >> 6;
    const int obase = (blockIdx.x * 4 + wv) * 16;     // 16 out voxels per wave
    if (obase >= num_out) return;

    const int row  = lane & 15;     // A-frag: m = lane&15 (out voxel in tile)
    const int quad = lane >> 4;     // A-frag: k-cols = quad*8 + j
    int o = obase + row;
    if (o >= num_out) o = num_out - 1;   // clamp (stores guarded, loads not)

    // 8 child indices for this row (32B; 4 quads redundant -> L1-hot).
    const int4* cp = (const int4*)(child + (size_t)o * 8);
    int4 c0 = cp[0], c1 = cp[1];
    int pk[8] = {c0.x, c0.y, c0.z, c0.w, c1.x, c1.y, c1.z, c1.w};

    // Batched unconditional gathers: 8 x 16B per lane, one bf16 A-fragment
    // each (channels quad*8..quad*8+7 of the child row) — already in MFMA
    // A-operand order, no pack needed.
    bf16x8 xr[8];
#pragma unroll
    for (int k = 0; k < 8; ++k) {
        int p = pk[k] < 0 ? 0 : pk[k];
        xr[k] = *(const bf16x8*)(xb + (size_t)p * 32 + quad * 8);
    }

    f32x4 acc0 = {0.f, 0.f, 0.f, 0.f};   // channels 0..15
    f32x4 acc1 = {0.f, 0.f, 0.f, 0.f};   // channels 16..31

#pragma unroll
    for (int k = 0; k < 8; ++k) {
        const bool valid = pk[k] >= 0;
        ABFrag a; a.v = xr[k];
        a.i[0] = valid ? a.i[0] : 0;
        a.i[1] = valid ? a.i[1] : 0;
        a.i[2] = valid ? a.i[2] : 0;
        a.i[3] = valid ? a.i[3] : 0;
        bf16x8 b0 = *(const bf16x8*)(WB + ((size_t)(k * 2 + 0) * 64 + lane) * 8);
        bf16x8 b1 = *(const bf16x8*)(WB + ((size_t)(k * 2 + 1) * 64 + lane) * 8);
        acc0 = __builtin_amdgcn_mfma_f32_16x16x32_bf16(a.v, b0, acc0, 0, 0, 0);
        acc1 = __builtin_amdgcn_mfma_f32_16x16x32_bf16(a.v, b1, acc1, 0, 0, 0);
    }

    // C/D layout: col = lane&15 (channel), row = quad*4 + r (voxel).
#pragma unroll
    for (int r = 0; r < 4; ++r) {
        int oo = obase + quad * 4 + r;
        if (oo < num_out) {
            float* op = out + (size_t)oo * 32 + (lane & 15);
            op[0]  = acc0[r];
            op[16] = acc1[r];
        }
    }
}

// ---- fallback (atomic scatter) in case ws_size is too small ----
__global__ void prep_w_kernel(const float* __restrict__ W,
                              unsigned short* __restrict__ WB) {
    int t = blockIdx.x * blockDim.x + threadIdx.x;
    if (t >= 8 * 2 * 64 * 8) return;
    int j = t & 7, lane = (t >> 3) & 63, half = (t >> 9) & 1, k = t >> 10;
    int c = (lane >> 4) * 8 + j;
    int d = half * 16 + (lane & 15);
    WB[t] = f2bf(W[k * 1024 + c * 32 + d]);
}

__global__ __launch_bounds__(256) void conv_atomic_kernel(
    const float* __restrict__ x, const unsigned short* __restrict__ WB,
    const int* __restrict__ k_idx, const int* __restrict__ out_idx,
    float* __restrict__ out, int n)
{
    const int lane = threadIdx.x & 63;
    const int wv   = threadIdx.x >> 6;
    const int base = (blockIdx.x * 4 + wv) * 16;
    if (base >= n) return;
    const int row = lane & 15, quad = lane >> 4;
    const int p = base + row;
    int krow = -1;
    ABFrag a; a.i[0] = a.i[1] = a.i[2] = a.i[3] = 0;
    if (p < n) {
        krow = k_idx[p];
        const float* xp = x + (size_t)p * 32 + quad * 8;
        float4 x0 = *(const float4*)xp;
        float4 x1 = *(const float4*)(xp + 4);
        a.i[0] = pack2_bf16(x0.x, x0.y);
        a.i[1] = pack2_bf16(x0.z, x0.w);
        a.i[2] = pack2_bf16(x1.x, x1.y);
        a.i[3] = pack2_bf16(x1.z, x1.w);
    }
    f32x4 acc0 = {0.f,0.f,0.f,0.f}, acc1 = {0.f,0.f,0.f,0.f};
#pragma unroll
    for (int k = 0; k < 8; ++k) {
        bf16x8 b0 = *(const bf16x8*)(WB + ((size_t)(k*2+0)*64 + lane)*8);
        bf16x8 b1 = *(const bf16x8*)(WB + ((size_t)(k*2+1)*64 + lane)*8);
        const bool keep = (krow == k);
        ABFrag ak;
        ak.i[0] = keep ? a.i[0] : 0; ak.i[1] = keep ? a.i[1] : 0;
        ak.i[2] = keep ? a.i[2] : 0; ak.i[3] = keep ? a.i[3] : 0;
        acc0 = __builtin_amdgcn_mfma_f32_16x16x32_bf16(ak.v, b0, acc0, 0, 0, 0);
        acc1 = __builtin_amdgcn_mfma_f32_16x16x32_bf16(ak.v, b1, acc1, 0, 0, 0);
    }
#pragma unroll
    for (int r = 0; r < 4; ++r) {
        int p2 = base + quad * 4 + r;
        if (p2 < n) {
            int oi = out_idx[p2];
            float* op = out + (size_t)oi * 32 + (lane & 15);
            atomicAdd(op,      acc0[r]);
            atomicAdd(op + 16, acc1[r]);
        }
    }
}

extern "C" void kernel_launch(void* const* d_in, const int* in_sizes, int n_in,
                              void* d_out, int out_size, void* d_ws, size_t ws_size,
                              hipStream_t stream) {
    const float* x       = (const float*)d_in[0];
    const float* W       = (const float*)d_in[1];
    const int*   k_idx   = (const int*)d_in[2];
    const int*   out_idx = (const int*)d_in[3];
    const int n = in_sizes[2];
    const int num_out = out_size / 32;           // C=32 channels per voxel
    float* out = (float*)d_out;

    // ws layout: WB (16 KB) | child (num_out*8 int) | x_bf16 (n*32 bf16)
    unsigned short* WB = (unsigned short*)d_ws;
    const size_t wb_bytes = 16384;
    int* child = (int*)((char*)d_ws + wb_bytes);
    const size_t child_bytes = (size_t)num_out * 8 * sizeof(int);
    size_t xb_off = wb_bytes + ((child_bytes + 255) & ~(size_t)255);
    unsigned short* xb = (unsigned short*)((char*)d_ws + xb_off);
    const size_t xb_bytes = (size_t)n * 32 * sizeof(unsigned short);

    if (ws_size >= xb_off + xb_bytes) {
        // ---- atomic-free path: 3 launches ----
        int n4 = num_out * 2;                    // int4 count of child map
        int blocksA = (n4 + 255) / 256;
        if (blocksA < 32) blocksA = 32;          // prep needs 8192 threads
        prep_fill_kernel<<<blocksA, 256, 0, stream>>>(W, WB, (int4*)child, n4);
        convert_build_kernel<<<(n + 255) / 256, 256, 0, stream>>>(
            (const float4*)x, (int2*)xb, k_idx, out_idx, child, n);
        int blocks = (num_out + 63) / 64;        // 64 voxels/block (4 waves)
        conv_gather_kernel<<<blocks, 256, 0, stream>>>(xb, WB, child, out, num_out);
    } else {
        // ---- fallback: atomic scatter ----
        prep_w_kernel<<<32, 256, 0, stream>>>(W, WB);
        hipMemsetAsync(d_out, 0, (size_t)out_size * sizeof(float), stream);
        int blocks = (n + 63) / 64;
        conv_atomic_kernel<<<blocks, 256, 0, stream>>>(x, WB, k_idx, out_idx, out, n);
    }
}

// Round 6
// 189.539 us; speedup vs baseline: 1.0205x; 1.0205x over previous
//
#include <hip/hip_runtime.h>
#include <hip/hip_bf16.h>

// Sparse Conv3d(32,32,k=2,s=2) kernel-map form:
//   out[out_idx[p], d] += sum_c x[p,c] * W[k_idx[p], c, d]
//
// R6: atomic-free inverse-map design (child[o][k]=p, plain stores). x is
// pre-converted to bf16 (streaming, fused with map build); the bf16 copy is
// written AFTER the harness's L3-evicting ws-poison, so the conv gather hits
// L2/L3. conv is now a PERSISTENT grid-stride kernel: 2 MFMA tiles (32 out
// voxels) per wave per iteration, all 20 loads batched up front, B-fragments
// shared across both tiles, multiple iterations per wave so next-iteration
// load latency overlaps current MFMA+stores. launch_bounds(256,3) keeps
// ~170 VGPRs so the 64 regs of gathered fragments don't force load sinking.

typedef __attribute__((ext_vector_type(8))) short bf16x8;   // 8 bf16 = 4 VGPRs
typedef __attribute__((ext_vector_type(4))) float f32x4;    // 4 fp32 acc

union ABFrag { bf16x8 v; int i[4]; };
union BFI { __hip_bfloat162 h; int i; };

__device__ __forceinline__ int pack2_bf16(float a, float b) {
    BFI u; u.h = __float22bfloat162_rn(make_float2(a, b));   // h.x=lo, h.y=hi
    return u.i;
}

__device__ __forceinline__ unsigned short f2bf(float f) {
    union { float f; unsigned u; } v; v.f = f;
    unsigned r = v.u + 0x7FFFu + ((v.u >> 16) & 1u);   // RNE
    return (unsigned short)(r >> 16);
}

// Fused: (a) repack W[k][c][d] fp32 -> WB in B-fragment lane order (16 KB):
// WB[((k*2+half)*64 + lane)*8 + j] = bf16(W[k][(lane>>4)*8+j][half*16+(lane&15)])
// (b) grid-stride fill of child map with -1 (int4 stores).
__global__ __launch_bounds__(256) void prep_fill_kernel(
    const float* __restrict__ W, unsigned short* __restrict__ WB,
    int4* __restrict__ child4, int n4) {
    int t = blockIdx.x * blockDim.x + threadIdx.x;
    if (t < 8 * 2 * 64 * 8) {
        int j    = t & 7;
        int lane = (t >> 3) & 63;
        int half = (t >> 9) & 1;
        int k    = t >> 10;
        int c = (lane >> 4) * 8 + j;
        int d = half * 16 + (lane & 15);
        WB[t] = f2bf(W[k * 1024 + c * 32 + d]);
    }
    const int4 m1 = make_int4(-1, -1, -1, -1);
    for (int i = t; i < n4; i += gridDim.x * blockDim.x) child4[i] = m1;
}

// Fused streaming pass: (a) inverse map (plain store, unique slots);
// (b) x fp32 -> bf16 copy (float4 in, int2 out), fully coalesced.
__global__ __launch_bounds__(256) void convert_build_kernel(
    const float4* __restrict__ x4, int2* __restrict__ xb2,
    const int* __restrict__ k_idx, const int* __restrict__ out_idx,
    int* __restrict__ child, int n) {
    int t = blockIdx.x * blockDim.x + threadIdx.x;
    if (t < n) child[(size_t)out_idx[t] * 8 + k_idx[t]] = t;
    const int n4 = n * 8;                       // float4 chunks (n*32/4)
    const int stride = gridDim.x * blockDim.x;
    for (int i = t; i < n4; i += stride) {
        float4 v = x4[i];
        xb2[i] = make_int2(pack2_bf16(v.x, v.y), pack2_bf16(v.z, v.w));
    }
}

__global__ __launch_bounds__(256, 3) void conv_gather_kernel(
    const unsigned short* __restrict__ xb,    // bf16 x, row-major n x 32
    const unsigned short* __restrict__ WB,
    const int* __restrict__ child,
    float* __restrict__ out,
    int num_out, int nTiles)                  // nTiles = ceil(num_out/128)
{
    const int lane = threadIdx.x & 63;
    const int wv   = threadIdx.x >> 6;
    const int row  = lane & 15;     // A-frag m / C-frag channel col
    const int quad = lane >> 4;     // A-frag k-group / C-frag row group

    for (int t = blockIdx.x; t < nTiles; t += gridDim.x) {
        const int obase = t * 128 + wv * 32;  // this wave: voxels obase..obase+31

        // ---- batched index loads: 2 tiles x 32B contiguous per row ----
        int oA = obase + row;        if (oA >= num_out) oA = num_out - 1;
        int oB = obase + 16 + row;   if (oB >= num_out) oB = num_out - 1;
        const int4* cA = (const int4*)(child + (size_t)oA * 8);
        const int4* cB = (const int4*)(child + (size_t)oB * 8);
        int4 ca0 = cA[0], ca1 = cA[1];
        int4 cb0 = cB[0], cb1 = cB[1];
        int pkA[8] = {ca0.x, ca0.y, ca0.z, ca0.w, ca1.x, ca1.y, ca1.z, ca1.w};
        int pkB[8] = {cb0.x, cb0.y, cb0.z, cb0.w, cb1.x, cb1.y, cb1.z, cb1.w};

        // ---- batched gathers: 16 x 16B, unconditional (clamped) ----
        bf16x8 xrA[8], xrB[8];
#pragma unroll
        for (int k = 0; k < 8; ++k) {
            int p = pkA[k] < 0 ? 0 : pkA[k];
            xrA[k] = *(const bf16x8*)(xb + (size_t)p * 32 + quad * 8);
        }
#pragma unroll
        for (int k = 0; k < 8; ++k) {
            int p = pkB[k] < 0 ? 0 : pkB[k];
            xrB[k] = *(const bf16x8*)(xb + (size_t)p * 32 + quad * 8);
        }

        f32x4 accA0 = {0.f,0.f,0.f,0.f}, accA1 = {0.f,0.f,0.f,0.f};
        f32x4 accB0 = {0.f,0.f,0.f,0.f}, accB1 = {0.f,0.f,0.f,0.f};

        // ---- MFMA: B fragments shared by both tiles ----
#pragma unroll
        for (int k = 0; k < 8; ++k) {
            bf16x8 w0 = *(const bf16x8*)(WB + ((size_t)(k * 2 + 0) * 64 + lane) * 8);
            bf16x8 w1 = *(const bf16x8*)(WB + ((size_t)(k * 2 + 1) * 64 + lane) * 8);
            ABFrag aA; aA.v = xrA[k];
            bool vA = pkA[k] >= 0;
            aA.i[0] = vA ? aA.i[0] : 0;  aA.i[1] = vA ? aA.i[1] : 0;
            aA.i[2] = vA ? aA.i[2] : 0;  aA.i[3] = vA ? aA.i[3] : 0;
            ABFrag aB; aB.v = xrB[k];
            bool vB = pkB[k] >= 0;
            aB.i[0] = vB ? aB.i[0] : 0;  aB.i[1] = vB ? aB.i[1] : 0;
            aB.i[2] = vB ? aB.i[2] : 0;  aB.i[3] = vB ? aB.i[3] : 0;
            accA0 = __builtin_amdgcn_mfma_f32_16x16x32_bf16(aA.v, w0, accA0, 0, 0, 0);
            accA1 = __builtin_amdgcn_mfma_f32_16x16x32_bf16(aA.v, w1, accA1, 0, 0, 0);
            accB0 = __builtin_amdgcn_mfma_f32_16x16x32_bf16(aB.v, w0, accB0, 0, 0, 0);
            accB1 = __builtin_amdgcn_mfma_f32_16x16x32_bf16(aB.v, w1, accB1, 0, 0, 0);
        }

        // ---- stores: C/D col = lane&15 (channel), D row = quad*4+r (voxel) ----
#pragma unroll
        for (int r = 0; r < 4; ++r) {
            int vA = obase + quad * 4 + r;
            if (vA < num_out) {
                float* op = out + (size_t)vA * 32 + row;
                op[0]  = accA0[r];
                op[16] = accA1[r];
            }
            int vB = obase + 16 + quad * 4 + r;
            if (vB < num_out) {
                float* op = out + (size_t)vB * 32 + row;
                op[0]  = accB0[r];
                op[16] = accB1[r];
            }
        }
    }
}

// ---- fallback (atomic scatter) in case ws_size is too small ----
__global__ void prep_w_kernel(const float* __restrict__ W,
                              unsigned short* __restrict__ WB) {
    int t = blockIdx.x * blockDim.x + threadIdx.x;
    if (t >= 8 * 2 * 64 * 8) return;
    int j = t & 7, lane = (t >> 3) & 63, half = (t >> 9) & 1, k = t >> 10;
    int c = (lane >> 4) * 8 + j;
    int d = half * 16 + (lane & 15);
    WB[t] = f2bf(W[k * 1024 + c * 32 + d]);
}

__global__ __launch_bounds__(256) void conv_atomic_kernel(
    const float* __restrict__ x, const unsigned short* __restrict__ WB,
    const int* __restrict__ k_idx, const int* __restrict__ out_idx,
    float* __restrict__ out, int n)
{
    const int lane = threadIdx.x & 63;
    const int wv   = threadIdx.x >> 6;
    const int base = (blockIdx.x * 4 + wv) * 16;
    if (base >= n) return;
    const int row = lane & 15, quad = lane >> 4;
    const int p = base + row;
    int krow = -1;
    ABFrag a; a.i[0] = a.i[1] = a.i[2] = a.i[3] = 0;
    if (p < n) {
        krow = k_idx[p];
        const float* xp = x + (size_t)p * 32 + quad * 8;
        float4 x0 = *(const float4*)xp;
        float4 x1 = *(const float4*)(xp + 4);
        a.i[0] = pack2_bf16(x0.x, x0.y);
        a.i[1] = pack2_bf16(x0.z, x0.w);
        a.i[2] = pack2_bf16(x1.x, x1.y);
        a.i[3] = pack2_bf16(x1.z, x1.w);
    }
    f32x4 acc0 = {0.f,0.f,0.f,0.f}, acc1 = {0.f,0.f,0.f,0.f};
#pragma unroll
    for (int k = 0; k < 8; ++k) {
        bf16x8 b0 = *(const bf16x8*)(WB + ((size_t)(k*2+0)*64 + lane)*8);
        bf16x8 b1 = *(const bf16x8*)(WB + ((size_t)(k*2+1)*64 + lane)*8);
        const bool keep = (krow == k);
        ABFrag ak;
        ak.i[0] = keep ? a.i[0] : 0; ak.i[1] = keep ? a.i[1] : 0;
        ak.i[2] = keep ? a.i[2] : 0; ak.i[3] = keep ? a.i[3] : 0;
        acc0 = __builtin_amdgcn_mfma_f32_16x16x32_bf16(ak.v, b0, acc0, 0, 0, 0);
        acc1 = __builtin_amdgcn_mfma_f32_16x16x32_bf16(ak.v, b1, acc1, 0, 0, 0);
    }
#pragma unroll
    for (int r = 0; r < 4; ++r) {
        int p2 = base + quad * 4 + r;
        if (p2 < n) {
            int oi = out_idx[p2];
            float* op = out + (size_t)oi * 32 + (lane & 15);
            atomicAdd(op,      acc0[r]);
            atomicAdd(op + 16, acc1[r]);
        }
    }
}

extern "C" void kernel_launch(void* const* d_in, const int* in_sizes, int n_in,
                              void* d_out, int out_size, void* d_ws, size_t ws_size,
                              hipStream_t stream) {
    const float* x       = (const float*)d_in[0];
    const float* W       = (const float*)d_in[1];
    const int*   k_idx   = (const int*)d_in[2];
    const int*   out_idx = (const int*)d_in[3];
    const int n = in_sizes[2];
    const int num_out = out_size / 32;           // C=32 channels per voxel
    float* out = (float*)d_out;

    // ws layout: WB (16 KB) | child (num_out*8 int) | x_bf16 (n*32 bf16)
    unsigned short* WB = (unsigned short*)d_ws;
    const size_t wb_bytes = 16384;
    int* child = (int*)((char*)d_ws + wb_bytes);
    const size_t child_bytes = (size_t)num_out * 8 * sizeof(int);
    size_t xb_off = wb_bytes + ((child_bytes + 255) & ~(size_t)255);
    unsigned short* xb = (unsigned short*)((char*)d_ws + xb_off);
    const size_t xb_bytes = (size_t)n * 32 * sizeof(unsigned short);

    if (ws_size >= xb_off + xb_bytes) {
        // ---- atomic-free path: 3 launches ----
        int n4 = num_out * 2;                    // int4 count of child map
        int blocksA = (n4 + 255) / 256;
        if (blocksA < 32) blocksA = 32;          // prep needs 8192 threads
        prep_fill_kernel<<<blocksA, 256, 0, stream>>>(W, WB, (int4*)child, n4);
        convert_build_kernel<<<(n + 255) / 256, 256, 0, stream>>>(
            (const float4*)x, (int2*)xb, k_idx, out_idx, child, n);
        int nTiles = (num_out + 127) / 128;      // 128 voxels per block-iter
        int blocks = nTiles < 768 ? nTiles : 768;    // persistent, ~3 blocks/CU
        conv_gather_kernel<<<blocks, 256, 0, stream>>>(xb, WB, child, out,
                                                       num_out, nTiles);
    } else {
        // ---- fallback: atomic scatter ----
        prep_w_kernel<<<32, 256, 0, stream>>>(W, WB);
        hipMemsetAsync(d_out, 0, (size_t)out_size * sizeof(float), stream);
        int blocks = (n + 63) / 64;
        conv_atomic_kernel<<<blocks, 256, 0, stream>>>(x, WB, k_idx, out_idx, out, n);
    }
}

// Round 7
// 185.850 us; speedup vs baseline: 1.0408x; 1.0198x over previous
//
#include <hip/hip_runtime.h>
#include <hip/hip_bf16.h>

// Sparse Conv3d(32,32,k=2,s=2) kernel-map form:
//   out[out_idx[p], d] += sum_c x[p,c] * W[k_idx[p], c, d]
//
// R7: atomic-free inverse-map (child[o][k]=p, plain stores; unique slots since
// k=2,s=2). No bf16 convert pass (R5/R6 showed it's a net loss; x is L3-warm
// after the harness restore). conv is strip-mined: each wave owns 4 tiles
// (64 consecutive out voxels); ALL child-index loads issue first (independent,
// one latency), then per-tile x-gather -> pack -> 16x16x32 bf16 MFMA -> store,
// fully unrolled at launch_bounds(256,2) so the scheduler pipelines tile j+1
// loads over tile j MFMAs. XCD-swizzled block ids give each XCD a contiguous
// 1/8 of o-space (L2 locality).

typedef __attribute__((ext_vector_type(8))) short bf16x8;   // 8 bf16 = 4 VGPRs
typedef __attribute__((ext_vector_type(4))) float f32x4;    // 4 fp32 acc

union ABFrag { bf16x8 v; int i[4]; };
union BFI { __hip_bfloat162 h; int i; };

__device__ __forceinline__ int pack2_bf16(float a, float b) {
    BFI u; u.h = __float22bfloat162_rn(make_float2(a, b));   // h.x=lo, h.y=hi
    return u.i;
}

__device__ __forceinline__ unsigned short f2bf(float f) {
    union { float f; unsigned u; } v; v.f = f;
    unsigned r = v.u + 0x7FFFu + ((v.u >> 16) & 1u);   // RNE
    return (unsigned short)(r >> 16);
}

// Fused: (a) repack W[k][c][d] fp32 -> WB in B-fragment lane order (16 KB):
// WB[((k*2+half)*64 + lane)*8 + j] = bf16(W[k][(lane>>4)*8+j][half*16+(lane&15)])
// (b) grid-stride fill of child map with -1 (int4 stores).
__global__ __launch_bounds__(256) void prep_fill_kernel(
    const float* __restrict__ W, unsigned short* __restrict__ WB,
    int4* __restrict__ child4, int n4) {
    int t = blockIdx.x * blockDim.x + threadIdx.x;
    if (t < 8 * 2 * 64 * 8) {
        int j    = t & 7;
        int lane = (t >> 3) & 63;
        int half = (t >> 9) & 1;
        int k    = t >> 10;
        int c = (lane >> 4) * 8 + j;
        int d = half * 16 + (lane & 15);
        WB[t] = f2bf(W[k * 1024 + c * 32 + d]);
    }
    const int4 m1 = make_int4(-1, -1, -1, -1);
    for (int i = t; i < n4; i += gridDim.x * blockDim.x) child4[i] = m1;
}

// Inverse map: each point owns a unique (out,k) slot -> plain store.
__global__ __launch_bounds__(256) void build_map_kernel(
    const int* __restrict__ k_idx, const int* __restrict__ out_idx,
    int* __restrict__ child, int n) {
    int t = blockIdx.x * blockDim.x + threadIdx.x;
    if (t < n) child[(size_t)out_idx[t] * 8 + k_idx[t]] = t;
}

#define T_STRIP 4

__global__ __launch_bounds__(256, 2) void conv_gather_kernel(
    const float* __restrict__ x,              // fp32, n x 32
    const unsigned short* __restrict__ WB,
    const int* __restrict__ child,
    float* __restrict__ out,
    int num_out, int nStrips)
{
    const int lane = threadIdx.x & 63;
    const int wv   = threadIdx.x >> 6;
    const int row  = lane & 15;     // A-frag m / C-frag channel col
    const int quad = lane >> 4;     // A-frag k-group / C-frag row group

    // XCD swizzle: consecutive bids round-robin across 8 XCDs; remap so each
    // XCD owns a contiguous range of strips (contiguous o -> L2 locality).
    const int nb  = gridDim.x;                 // multiple of 8
    const int bid = (int)blockIdx.x;
    const int sw  = (bid & 7) * (nb >> 3) + (bid >> 3);
    const int waveStride = nb * 4;

    for (int sid = sw * 4 + wv; sid < nStrips; sid += waveStride) {
        // ---- phase 1: ALL child-index loads for the strip (independent) ----
        int pk[T_STRIP][8];
#pragma unroll
        for (int j = 0; j < T_STRIP; ++j) {
            int o = (sid * T_STRIP + j) * 16 + row;
            if (o >= num_out) o = num_out - 1;
            const int4* cp = (const int4*)(child + (size_t)o * 8);
            int4 c0 = cp[0], c1 = cp[1];
            pk[j][0] = c0.x; pk[j][1] = c0.y; pk[j][2] = c0.z; pk[j][3] = c0.w;
            pk[j][4] = c1.x; pk[j][5] = c1.y; pk[j][6] = c1.z; pk[j][7] = c1.w;
        }

        // ---- phase 2: per tile gather -> pack -> MFMA -> store (unrolled;
        //      scheduler pipelines tile j+1 loads over tile j MFMAs) ----
#pragma unroll
        for (int j = 0; j < T_STRIP; ++j) {
            const int obase = (sid * T_STRIP + j) * 16;

            float4 xa[8], xb[8];
#pragma unroll
            for (int k = 0; k < 8; ++k) {
                int p = pk[j][k] < 0 ? 0 : pk[j][k];
                const float* xp = x + (size_t)p * 32 + quad * 8;
                xa[k] = *(const float4*)xp;
                xb[k] = *(const float4*)(xp + 4);
            }

            f32x4 acc0 = {0.f, 0.f, 0.f, 0.f};   // channels 0..15
            f32x4 acc1 = {0.f, 0.f, 0.f, 0.f};   // channels 16..31
#pragma unroll
            for (int k = 0; k < 8; ++k) {
                const bool valid = pk[j][k] >= 0;
                ABFrag a;
                a.i[0] = valid ? pack2_bf16(xa[k].x, xa[k].y) : 0;
                a.i[1] = valid ? pack2_bf16(xa[k].z, xa[k].w) : 0;
                a.i[2] = valid ? pack2_bf16(xb[k].x, xb[k].y) : 0;
                a.i[3] = valid ? pack2_bf16(xb[k].z, xb[k].w) : 0;
                bf16x8 b0 = *(const bf16x8*)(WB + ((size_t)(k * 2 + 0) * 64 + lane) * 8);
                bf16x8 b1 = *(const bf16x8*)(WB + ((size_t)(k * 2 + 1) * 64 + lane) * 8);
                acc0 = __builtin_amdgcn_mfma_f32_16x16x32_bf16(a.v, b0, acc0, 0, 0, 0);
                acc1 = __builtin_amdgcn_mfma_f32_16x16x32_bf16(a.v, b1, acc1, 0, 0, 0);
            }

            // C/D: col = lane&15 (channel), row = quad*4 + r (voxel).
#pragma unroll
            for (int r = 0; r < 4; ++r) {
                int oo = obase + quad * 4 + r;
                if (oo < num_out) {
                    float* op = out + (size_t)oo * 32 + row;
                    op[0]  = acc0[r];
                    op[16] = acc1[r];
                }
            }
        }
    }
}

// ---- fallback (atomic scatter) in case ws_size is too small ----
__global__ void prep_w_kernel(const float* __restrict__ W,
                              unsigned short* __restrict__ WB) {
    int t = blockIdx.x * blockDim.x + threadIdx.x;
    if (t >= 8 * 2 * 64 * 8) return;
    int j = t & 7, lane = (t >> 3) & 63, half = (t >> 9) & 1, k = t >> 10;
    int c = (lane >> 4) * 8 + j;
    int d = half * 16 + (lane & 15);
    WB[t] = f2bf(W[k * 1024 + c * 32 + d]);
}

__global__ __launch_bounds__(256) void conv_atomic_kernel(
    const float* __restrict__ x, const unsigned short* __restrict__ WB,
    const int* __restrict__ k_idx, const int* __restrict__ out_idx,
    float* __restrict__ out, int n)
{
    const int lane = threadIdx.x & 63;
    const int wv   = threadIdx.x >> 6;
    const int base = (blockIdx.x * 4 + wv) * 16;
    if (base >= n) return;
    const int row = lane & 15, quad = lane >> 4;
    const int p = base + row;
    int krow = -1;
    ABFrag a; a.i[0] = a.i[1] = a.i[2] = a.i[3] = 0;
    if (p < n) {
        krow = k_idx[p];
        const float* xp = x + (size_t)p * 32 + quad * 8;
        float4 x0 = *(const float4*)xp;
        float4 x1 = *(const float4*)(xp + 4);
        a.i[0] = pack2_bf16(x0.x, x0.y);
        a.i[1] = pack2_bf16(x0.z, x0.w);
        a.i[2] = pack2_bf16(x1.x, x1.y);
        a.i[3] = pack2_bf16(x1.z, x1.w);
    }
    f32x4 acc0 = {0.f,0.f,0.f,0.f}, acc1 = {0.f,0.f,0.f,0.f};
#pragma unroll
    for (int k = 0; k < 8; ++k) {
        bf16x8 b0 = *(const bf16x8*)(WB + ((size_t)(k*2+0)*64 + lane)*8);
        bf16x8 b1 = *(const bf16x8*)(WB + ((size_t)(k*2+1)*64 + lane)*8);
        const bool keep = (krow == k);
        ABFrag ak;
        ak.i[0] = keep ? a.i[0] : 0; ak.i[1] = keep ? a.i[1] : 0;
        ak.i[2] = keep ? a.i[2] : 0; ak.i[3] = keep ? a.i[3] : 0;
        acc0 = __builtin_amdgcn_mfma_f32_16x16x32_bf16(ak.v, b0, acc0, 0, 0, 0);
        acc1 = __builtin_amdgcn_mfma_f32_16x16x32_bf16(ak.v, b1, acc1, 0, 0, 0);
    }
#pragma unroll
    for (int r = 0; r < 4; ++r) {
        int p2 = base + quad * 4 + r;
        if (p2 < n) {
            int oi = out_idx[p2];
            float* op = out + (size_t)oi * 32 + (lane & 15);
            atomicAdd(op,      acc0[r]);
            atomicAdd(op + 16, acc1[r]);
        }
    }
}

extern "C" void kernel_launch(void* const* d_in, const int* in_sizes, int n_in,
                              void* d_out, int out_size, void* d_ws, size_t ws_size,
                              hipStream_t stream) {
    const float* x       = (const float*)d_in[0];
    const float* W       = (const float*)d_in[1];
    const int*   k_idx   = (const int*)d_in[2];
    const int*   out_idx = (const int*)d_in[3];
    const int n = in_sizes[2];
    const int num_out = out_size / 32;           // C=32 channels per voxel
    float* out = (float*)d_out;

    // ws layout: WB (16 KB) | child (num_out*8 int)
    unsigned short* WB = (unsigned short*)d_ws;
    const size_t wb_bytes = 16384;
    int* child = (int*)((char*)d_ws + wb_bytes);
    const size_t child_bytes = (size_t)num_out * 8 * sizeof(int);

    if (ws_size >= wb_bytes + child_bytes) {
        // ---- atomic-free path: 3 launches ----
        int n4 = num_out * 2;                    // int4 count of child map
        int blocksA = (n4 + 255) / 256;
        if (blocksA < 32) blocksA = 32;          // prep needs 8192 threads
        prep_fill_kernel<<<blocksA, 256, 0, stream>>>(W, WB, (int4*)child, n4);
        build_map_kernel<<<(n + 255) / 256, 256, 0, stream>>>(k_idx, out_idx, child, n);

        int nTiles  = (num_out + 15) / 16;
        int nStrips = (nTiles + T_STRIP - 1) / T_STRIP;
        conv_gather_kernel<<<1024, 256, 0, stream>>>(x, WB, child, out,
                                                     num_out, nStrips);
    } else {
        // ---- fallback: atomic scatter ----
        prep_w_kernel<<<32, 256, 0, stream>>>(W, WB);
        hipMemsetAsync(d_out, 0, (size_t)out_size * sizeof(float), stream);
        int blocks = (n + 63) / 64;
        conv_atomic_kernel<<<blocks, 256, 0, stream>>>(x, WB, k_idx, out_idx, out, n);
    }
}